// Round 1
// 729.438 us; speedup vs baseline: 1.1829x; 1.1829x over previous
//
#include <hip/hip_runtime.h>

// GCN + low-rank global attention (LRGA), N=100k, E=1.6M, D=128, K=64.
// Inputs fp32 + int32 edge_index; OUTPUT fp32.
// Intermediates h (x@Wg), t (relu(x@Wa+ba)), x_local stored bf16 in workspace.
// R1: k_out rewritten as bf16 MFMA GEMM with VtZ@Wr folded into precomputed Weff.
#define DIN   128
#define DOUT  128
#define KR    64
#define TCOLS 256   // 4*K

typedef unsigned short ushort_t;
typedef __attribute__((ext_vector_type(8))) short bf16x8;
typedef __attribute__((ext_vector_type(4))) float f32x4;

__device__ __forceinline__ float bf2f(unsigned short u) {
  return __uint_as_float(((unsigned int)u) << 16);
}
__device__ __forceinline__ unsigned short f2bf(float f) {
  unsigned int b = __float_as_uint(f);
  b = b + 0x7FFFu + ((b >> 16) & 1u);
  return (unsigned short)(b >> 16);
}

// ---------------------------------------------------------------- init
__global__ __launch_bounds__(256) void k_init(int* __restrict__ degc, float* __restrict__ VtZ,
                                              float* __restrict__ colsum, int N) {
  int i = blockIdx.x * 256 + threadIdx.x;
  if (i < N) degc[i] = 1;            // self-loop gives deg >= 1
  if (i < 4096) VtZ[i] = 0.f;
  if (i < 128) colsum[i] = 0.f;
}

// ---------------------------------------------------------------- degree (in-degree via dst row)
__global__ __launch_bounds__(256) void k_deg(const int* __restrict__ ei, int* __restrict__ degc, int E) {
  int e = blockIdx.x * 256 + threadIdx.x;
  if (e < E) atomicAdd(&degc[ei[E + e]], 1);
}

// ---------------------------------------------------------------- hierarchical scan, stage 1:
// per-block exclusive scan of (degc-1) over 1024-element tiles; block sums out.
__global__ __launch_bounds__(256) void k_scan1(const int* __restrict__ degc, int* __restrict__ offs,
                                               int* __restrict__ bsums, int N) {
  __shared__ int s[256];
  int tid = threadIdx.x;
  int base = blockIdx.x * 1024 + tid * 4;
  int c[4], e[4];
#pragma unroll
  for (int q = 0; q < 4; ++q) c[q] = (base + q < N) ? (degc[base + q] - 1) : 0;
  e[0] = 0; e[1] = c[0]; e[2] = e[1] + c[1]; e[3] = e[2] + c[2];
  int tsum = e[3] + c[3];
  s[tid] = tsum; __syncthreads();
  for (int off = 1; off < 256; off <<= 1) {
    int v = (tid >= off) ? s[tid - off] : 0;
    __syncthreads();
    s[tid] += v;
    __syncthreads();
  }
  int tb = s[tid] - tsum;
#pragma unroll
  for (int q = 0; q < 4; ++q) if (base + q < N) offs[base + q] = tb + e[q];
  if (tid == 255) bsums[blockIdx.x] = s[255];
}

// stage 2: exclusive scan of block sums (NBLK <= 128)
__global__ __launch_bounds__(128) void k_scan2(const int* __restrict__ bsums, int* __restrict__ boff,
                                               int* __restrict__ offs, int NBLK, int N) {
  __shared__ int s[128];
  int tid = threadIdx.x;
  int v = (tid < NBLK) ? bsums[tid] : 0;
  s[tid] = v; __syncthreads();
  for (int off = 1; off < 128; off <<= 1) {
    int u = (tid >= off) ? s[tid - off] : 0;
    __syncthreads();
    s[tid] += u;
    __syncthreads();
  }
  boff[tid] = s[tid] - v;
  if (tid == 127) offs[N] = s[127];   // total = E
}

// stage 3: add block offsets; dinv = rsqrt(deg); cursor = 0
__global__ __launch_bounds__(256) void k_scan3(int* __restrict__ offs, const int* __restrict__ boff,
                                               const int* __restrict__ degc, float* __restrict__ dinv,
                                               int* __restrict__ cursor, int N) {
  int i = blockIdx.x * 256 + threadIdx.x;
  if (i < N) {
    offs[i] += boff[i >> 10];
    dinv[i] = rsqrtf((float)degc[i]);
    cursor[i] = 0;
  }
}

// ---------------------------------------------------------------- CSR scatter: (src, norm) packed int2
__global__ __launch_bounds__(256) void k_scatter(const int* __restrict__ ei, const int* __restrict__ offs,
                                                 int* __restrict__ cursor, const float* __restrict__ dinv,
                                                 int2* __restrict__ csr, int E) {
  int e = blockIdx.x * 256 + threadIdx.x;
  if (e < E) {
    int s = ei[e];          // src
    int d = ei[E + e];      // dst
    int pos = atomicAdd(&cursor[d], 1);
    int2 q;
    q.x = s;
    q.y = __float_as_int(dinv[s] * dinv[d]);
    csr[offs[d] + pos] = q;
  }
}

// ---------------------------------------------------------------- fused GEMM: h = x@Wg (bf16) ; t = relu(x@Wa + ba) (bf16)
__global__ __launch_bounds__(256) void k_gemm1(const float* __restrict__ x,
                                               const float* __restrict__ Wg,
                                               const float* __restrict__ Wa,
                                               const float* __restrict__ ba,
                                               ushort_t* __restrict__ hs, ushort_t* __restrict__ t, int N) {
  __shared__ float xS[64 * 68];   // [row][k] stride 68
  __shared__ float wS[64 * 68];   // [k][col] stride 68
  int tid = threadIdx.x;
  int row0 = blockIdx.y * 64;
  int cbase = blockIdx.x * 64;
  int tc = tid & 15, tr = tid >> 4;
  float acc[4][4] = {};
  for (int kc = 0; kc < 2; ++kc) {
    for (int idx = tid; idx < 64 * 16; idx += 256) {
      int r = idx >> 4, c4 = idx & 15;
      int row = row0 + r;
      float4 v = (row < N) ? *(const float4*)&x[(size_t)row * DIN + kc * 64 + c4 * 4]
                           : make_float4(0.f, 0.f, 0.f, 0.f);
      *(float4*)&xS[r * 68 + c4 * 4] = v;
    }
    if (cbase < DOUT) {
      for (int idx = tid; idx < 64 * 16; idx += 256) {
        int k = idx >> 4, c4 = idx & 15;
        float4 v = *(const float4*)&Wg[(size_t)(kc * 64 + k) * DOUT + cbase + c4 * 4];
        *(float4*)&wS[k * 68 + c4 * 4] = v;
      }
    } else {
      for (int idx = tid; idx < 64 * 16; idx += 256) {
        int k = idx >> 4, c4 = idx & 15;
        float4 v = *(const float4*)&Wa[(size_t)(kc * 64 + k) * TCOLS + (cbase - DOUT) + c4 * 4];
        *(float4*)&wS[k * 68 + c4 * 4] = v;
      }
    }
    __syncthreads();
#pragma unroll
    for (int kv = 0; kv < 16; ++kv) {
      float xv[4][4], wv[4][4];
#pragma unroll
      for (int i = 0; i < 4; ++i) {
        float4 v = *(const float4*)&xS[(tr * 4 + i) * 68 + kv * 4];
        xv[i][0] = v.x; xv[i][1] = v.y; xv[i][2] = v.z; xv[i][3] = v.w;
      }
#pragma unroll
      for (int kk = 0; kk < 4; ++kk) {
        float4 v = *(const float4*)&wS[(kv * 4 + kk) * 68 + tc * 4];
        wv[kk][0] = v.x; wv[kk][1] = v.y; wv[kk][2] = v.z; wv[kk][3] = v.w;
      }
#pragma unroll
      for (int i = 0; i < 4; ++i)
#pragma unroll
        for (int kk = 0; kk < 4; ++kk) {
          acc[i][0] += xv[i][kk] * wv[kk][0];
          acc[i][1] += xv[i][kk] * wv[kk][1];
          acc[i][2] += xv[i][kk] * wv[kk][2];
          acc[i][3] += xv[i][kk] * wv[kk][3];
        }
    }
    __syncthreads();
  }
  int gc0 = cbase + tc * 4;
  if (gc0 < DOUT) {
#pragma unroll
    for (int i = 0; i < 4; ++i) {
      int row = row0 + tr * 4 + i;
      if (row < N) {
        ushort4 o;
        o.x = f2bf(acc[i][0]); o.y = f2bf(acc[i][1]);
        o.z = f2bf(acc[i][2]); o.w = f2bf(acc[i][3]);
        *(ushort4*)&hs[(size_t)row * DOUT + gc0] = o;
      }
    }
  } else {
    int ca0 = gc0 - DOUT;
    float bav[4];
#pragma unroll
    for (int q = 0; q < 4; ++q) bav[q] = ba[ca0 + q];
#pragma unroll
    for (int i = 0; i < 4; ++i) {
      int row = row0 + tr * 4 + i;
      if (row < N) {
        ushort4 o;
        o.x = f2bf(fmaxf(acc[i][0] + bav[0], 0.f));
        o.y = f2bf(fmaxf(acc[i][1] + bav[1], 0.f));
        o.z = f2bf(fmaxf(acc[i][2] + bav[2], 0.f));
        o.w = f2bf(fmaxf(acc[i][3] + bav[3], 0.f));
        *(ushort4*)&t[(size_t)row * TCOLS + ca0] = o;
      }
    }
  }
}

// ---------------------------------------------------------------- VtZ (64x64) + colsum(U),colsum(V)
__global__ __launch_bounds__(256) void k_red(const ushort_t* __restrict__ t, float* __restrict__ VtZ,
                                             float* __restrict__ colsum, int N) {
  __shared__ float uvz[16 * 192];   // cols 0..191 of t (U,V,Z)
  int tid = threadIdx.x;
  int RB = (N + gridDim.x - 1) / gridDim.x;
  int row0 = blockIdx.x * RB;
  int rowend = min(row0 + RB, N);
  int k = tid >> 2;
  int l0 = (tid & 3) * 16;
  float acc[16] = {};
  float cs = 0.f;
  for (int r0 = row0; r0 < rowend; r0 += 16) {
    for (int idx = tid; idx < 16 * 48; idx += 256) {
      int r = idx / 48, c4 = idx - r * 48;
      int row = r0 + r;
      float4 f;
      if (row < rowend) {
        ushort4 u = ((const ushort4*)&t[(size_t)row * TCOLS])[c4];
        f = make_float4(bf2f(u.x), bf2f(u.y), bf2f(u.z), bf2f(u.w));
      } else {
        f = make_float4(0.f, 0.f, 0.f, 0.f);
      }
      *(float4*)&uvz[r * 192 + c4 * 4] = f;
    }
    __syncthreads();
#pragma unroll
    for (int r = 0; r < 16; ++r) {
      float vk = uvz[r * 192 + 64 + k];
      const float4* zp = (const float4*)&uvz[r * 192 + 128 + l0];
#pragma unroll
      for (int q = 0; q < 4; ++q) {
        float4 z = zp[q];
        acc[q * 4 + 0] += vk * z.x;
        acc[q * 4 + 1] += vk * z.y;
        acc[q * 4 + 2] += vk * z.z;
        acc[q * 4 + 3] += vk * z.w;
      }
    }
    if (tid < 128) {
#pragma unroll
      for (int r = 0; r < 16; ++r) cs += uvz[r * 192 + tid];
    }
    __syncthreads();
  }
#pragma unroll
  for (int q = 0; q < 16; ++q) atomicAdd(&VtZ[k * 64 + l0 + q], acc[q]);
  if (tid < 128) atomicAdd(&colsum[tid], cs);
}

// ---------------------------------------------------------------- D = N / dot(colsumU, colsumV)
__global__ __launch_bounds__(64) void k_d(const float* __restrict__ colsum, float* __restrict__ Dws, int N) {
  __shared__ float s[64];
  int k = threadIdx.x;
  s[k] = colsum[k] * colsum[64 + k];
  __syncthreads();
  for (int off = 32; off > 0; off >>= 1) {
    if (k < off) s[k] += s[k + off];
    __syncthreads();
  }
  if (k == 0) {
    float p = s[0];
    Dws[0] = (p != 0.f) ? ((float)N / p) : 0.f;
  }
}

// ---------------------------------------------------------------- Weff^T (K-major) build:
// Weff[256][128] = [ Wr[0:128] ; M ; Wr[192:256] ], M[kk][c] = D * sum_j VtZ[kk][j]*Wr[128+j][c]
// stored transposed: weffT[c*256 + k], bf16. One block per c (128 blocks), k = tid.
__global__ __launch_bounds__(256) void k_prep(const float* __restrict__ VtZ,
                                              const float* __restrict__ Dws,
                                              const float* __restrict__ Wr,
                                              ushort_t* __restrict__ weffT) {
  int c = blockIdx.x;        // 0..127
  int k = threadIdx.x;       // 0..255
  float v;
  if (k < 128 || k >= 192) {
    v = Wr[(size_t)k * DOUT + c];
  } else {
    float Dv = Dws[0];
    int kk = k - 128;
    float acc = 0.f;
#pragma unroll 8
    for (int j = 0; j < 64; ++j)
      acc += VtZ[kk * 64 + j] * Wr[(size_t)(128 + j) * DOUT + c];
    v = acc * Dv;
  }
  weffT[(size_t)c * 256 + k] = f2bf(v);
}

// ---------------------------------------------------------------- out = [xl | U | T] @ Weff + br  (bf16 MFMA, fp32 out)
// A assembled on the fly: k<128 -> xl[row][k]; 128<=k<192 -> t[row][k-128] (U); k>=192 -> t[row][k] (T).
// Each 32-wide K-step lies entirely in one region. No LDS; B (64 KB) stays L2-resident.
// Block = 256 thr (4 waves, 2x2), tile 128 rows x 128 cols; wave = 64x64 = 4x4 frags of 16x16x32.
__global__ __launch_bounds__(256) void k_out_mfma(const ushort_t* __restrict__ xl,
                                                  const ushort_t* __restrict__ t,
                                                  const ushort_t* __restrict__ weffT,
                                                  const float* __restrict__ br,
                                                  float* __restrict__ out, int N) {
  int tid = threadIdx.x;
  int lane = tid & 63;
  int wave = tid >> 6;
  int wr = wave >> 1, wc = wave & 1;
  int rowbase = blockIdx.x * 128 + wr * 64;
  int cbase = wc * 64;
  int lr = lane & 15;          // A-row / B-col / D-col within frag
  int lk = (lane >> 4) * 8;    // k-chunk start within 32-wide step

  int rows[4];
#pragma unroll
  for (int m = 0; m < 4; ++m) {
    int r = rowbase + m * 16 + lr;
    rows[m] = (r < N) ? r : (N - 1);   // clamp: loads valid, stores guarded
  }

  f32x4 acc[4][4] = {};

#pragma unroll
  for (int s = 0; s < 8; ++s) {
    int k0 = s * 32 + lk;
    bf16x8 a[4], b[4];
#pragma unroll
    for (int m = 0; m < 4; ++m) {
      const ushort_t* ap;
      if (s < 4)      ap = &xl[(size_t)rows[m] * DOUT + k0];
      else if (s < 6) ap = &t[(size_t)rows[m] * TCOLS + (k0 - 128)];
      else            ap = &t[(size_t)rows[m] * TCOLS + k0];
      a[m] = *(const bf16x8*)ap;
    }
#pragma unroll
    for (int n = 0; n < 4; ++n) {
      int c = cbase + n * 16 + lr;
      b[n] = *(const bf16x8*)&weffT[(size_t)c * 256 + k0];
    }
#pragma unroll
    for (int m = 0; m < 4; ++m)
#pragma unroll
      for (int n = 0; n < 4; ++n)
        acc[m][n] = __builtin_amdgcn_mfma_f32_16x16x32_bf16(a[m], b[n], acc[m][n], 0, 0, 0);
  }

  float brv[4];
#pragma unroll
  for (int n = 0; n < 4; ++n) brv[n] = br[cbase + n * 16 + lr];

  int rq = (lane >> 4) * 4;    // D-row base within frag
#pragma unroll
  for (int m = 0; m < 4; ++m) {
#pragma unroll
    for (int i = 0; i < 4; ++i) {
      int row = rowbase + m * 16 + rq + i;
      if (row < N) {
#pragma unroll
        for (int n = 0; n < 4; ++n)
          out[(size_t)row * DOUT + cbase + n * 16 + lr] = acc[m][n][i] + brv[n];
      }
    }
  }
}

// ---------------------------------------------------------------- CSR gather-aggregate: x_local = relu(agg + b_gcn), bf16.
// No LDS -> high occupancy. 1 wave per node, lane covers 2 columns, ILP-4 over edges.
__global__ __launch_bounds__(256) void k_aggn(const ushort_t* __restrict__ hs, const int2* __restrict__ csr,
                                              const int* __restrict__ offs, const float* __restrict__ dinv,
                                              const float* __restrict__ bg,
                                              ushort_t* __restrict__ xl, int N) {
  int node = blockIdx.x * 4 + (threadIdx.x >> 6);
  int lane = threadIdx.x & 63;
  if (node >= N) return;
  int c2 = 2 * lane;
  float dn = dinv[node];
  ushort2 u = *(const ushort2*)&hs[(size_t)node * DOUT + c2];
  float a0 = dn * dn * bf2f(u.x);
  float a1 = dn * dn * bf2f(u.y);
  int e = offs[node], e1 = offs[node + 1];
  for (; e + 4 <= e1; e += 4) {
    int2 q0 = csr[e], q1 = csr[e + 1], q2 = csr[e + 2], q3 = csr[e + 3];
    ushort2 r0 = *(const ushort2*)&hs[(size_t)q0.x * DOUT + c2];
    ushort2 r1 = *(const ushort2*)&hs[(size_t)q1.x * DOUT + c2];
    ushort2 r2 = *(const ushort2*)&hs[(size_t)q2.x * DOUT + c2];
    ushort2 r3 = *(const ushort2*)&hs[(size_t)q3.x * DOUT + c2];
    float n0 = __int_as_float(q0.y), n1 = __int_as_float(q1.y);
    float n2 = __int_as_float(q2.y), n3 = __int_as_float(q3.y);
    a0 += n0 * bf2f(r0.x) + n1 * bf2f(r1.x) + n2 * bf2f(r2.x) + n3 * bf2f(r3.x);
    a1 += n0 * bf2f(r0.y) + n1 * bf2f(r1.y) + n2 * bf2f(r2.y) + n3 * bf2f(r3.y);
  }
  for (; e < e1; ++e) {
    int2 q = csr[e];
    ushort2 r = *(const ushort2*)&hs[(size_t)q.x * DOUT + c2];
    float n0 = __int_as_float(q.y);
    a0 += n0 * bf2f(r.x);
    a1 += n0 * bf2f(r.y);
  }
  ushort2 o;
  o.x = f2bf(fmaxf(a0 + bg[c2], 0.f));
  o.y = f2bf(fmaxf(a1 + bg[c2 + 1], 0.f));
  *(ushort2*)&xl[(size_t)node * DOUT + c2] = o;
}

// ---------------------------------------------------------------- launch
extern "C" void kernel_launch(void* const* d_in, const int* in_sizes, int n_in,
                              void* d_out, int out_size, void* d_ws, size_t ws_size,
                              hipStream_t stream) {
  const float* x  = (const float*)d_in[0];
  const int* ei   = (const int*)d_in[1];
  const float* Wg = (const float*)d_in[2];
  const float* bg = (const float*)d_in[3];
  const float* Wa = (const float*)d_in[4];
  const float* ba = (const float*)d_in[5];
  const float* Wr = (const float*)d_in[6];
  const float* br = (const float*)d_in[7];
  float* out = (float*)d_out;     // fp32 output

  const int N = in_sizes[0] / DIN;
  const int E = in_sizes[1] / 2;

  char* p = (char*)d_ws;
  auto alloc = [&](size_t bytes) {
    char* r = p;
    p += (bytes + 255) & ~(size_t)255;
    return r;
  };
  float* Dws    = (float*)alloc(256);
  float* colsum = (float*)alloc(128 * 4);
  float* VtZ    = (float*)alloc(4096 * 4);
  int*   bsums  = (int*)alloc(1024);
  int*   boff   = (int*)alloc(1024);
  ushort_t* weffT = (ushort_t*)alloc(128 * 256 * 2);        // bf16 Weff^T (K-major)
  int*   degc   = (int*)alloc((size_t)N * 4);
  float* dinv   = (float*)alloc((size_t)N * 4);
  int*   offs   = (int*)alloc((size_t)(N + 1) * 4);
  int*   cursor = (int*)alloc((size_t)N * 4);
  int2*  csr    = (int2*)alloc((size_t)E * 8);              // (src, norm) per edge
  ushort_t* hs  = (ushort_t*)alloc((size_t)N * DOUT * 2);   // bf16 x@Wg
  ushort_t* t   = (ushort_t*)alloc((size_t)N * TCOLS * 2);  // bf16 relu(x@Wa+ba)
  ushort_t* xl  = (ushort_t*)alloc((size_t)N * DOUT * 2);   // bf16 x_local
  (void)ws_size; (void)n_in; (void)out_size;

  const int GN = (N + 255) / 256;
  const int GE = (E + 255) / 256;
  const int NBLK = (N + 1023) / 1024;   // <= 128 for N <= 131072

  k_init<<<GN, 256, 0, stream>>>(degc, VtZ, colsum, N);
  k_deg<<<GE, 256, 0, stream>>>(ei, degc, E);
  k_scan1<<<NBLK, 256, 0, stream>>>(degc, offs, bsums, N);
  k_scan2<<<1, 128, 0, stream>>>(bsums, boff, offs, NBLK, N);
  k_scan3<<<GN, 256, 0, stream>>>(offs, boff, degc, dinv, cursor, N);
  k_scatter<<<GE, 256, 0, stream>>>(ei, offs, cursor, dinv, csr, E);
  k_gemm1<<<dim3(6, (N + 63) / 64), 256, 0, stream>>>(x, Wg, Wa, ba, hs, t, N);
  k_red<<<256, 256, 0, stream>>>(t, VtZ, colsum, N);
  k_d<<<1, 64, 0, stream>>>(colsum, Dws, N);
  k_prep<<<128, 256, 0, stream>>>(VtZ, Dws, Wr, weffT);
  k_aggn<<<(N + 3) / 4, 256, 0, stream>>>(hs, csr, offs, dinv, bg, xl, N);
  k_out_mfma<<<(N + 127) / 128, 256, 0, stream>>>(xl, t, weffT, br, out, N);
}

// Round 2
// 623.659 us; speedup vs baseline: 1.3836x; 1.1696x over previous
//
#include <hip/hip_runtime.h>

// GCN + low-rank global attention (LRGA), N=100k, E=1.6M, D=128, K=64.
// R1: k_out -> bf16 MFMA with folded Weff.
// R2: k_gemm1 -> split-bf16 (hi/lo) MFMA 3-pass (fp32-accurate); k_red grid 256->1024
//     with 4x4-outer-product thread mapping (was 1 block/CU latency-bound).
#define DIN   128
#define DOUT  128
#define KR    64
#define TCOLS 256   // 4*K
#define WCOLS 384   // DOUT + TCOLS

typedef unsigned short ushort_t;
typedef __attribute__((ext_vector_type(8))) short bf16x8;
typedef __attribute__((ext_vector_type(4))) float f32x4;

__device__ __forceinline__ float bf2f(unsigned short u) {
  return __uint_as_float(((unsigned int)u) << 16);
}
__device__ __forceinline__ unsigned short f2bf(float f) {
  unsigned int b = __float_as_uint(f);
  b = b + 0x7FFFu + ((b >> 16) & 1u);
  return (unsigned short)(b >> 16);
}

// ---------------------------------------------------------------- init
__global__ __launch_bounds__(256) void k_init(int* __restrict__ degc, float* __restrict__ VtZ,
                                              float* __restrict__ colsum, int N) {
  int i = blockIdx.x * 256 + threadIdx.x;
  if (i < N) degc[i] = 1;            // self-loop gives deg >= 1
  if (i < 4096) VtZ[i] = 0.f;
  if (i < 128) colsum[i] = 0.f;
}

// ---------------------------------------------------------------- degree (in-degree via dst row)
__global__ __launch_bounds__(256) void k_deg(const int* __restrict__ ei, int* __restrict__ degc, int E) {
  int e = blockIdx.x * 256 + threadIdx.x;
  if (e < E) atomicAdd(&degc[ei[E + e]], 1);
}

// ---------------------------------------------------------------- x -> bf16 hi/lo split (for MFMA)
__global__ __launch_bounds__(256) void k_split(const float* __restrict__ x,
                                               ushort_t* __restrict__ xh, ushort_t* __restrict__ xl4,
                                               int total4) {
  int i = blockIdx.x * 256 + threadIdx.x;
  int stride = gridDim.x * 256;
  for (; i < total4; i += stride) {
    float4 v = ((const float4*)x)[i];
    ushort4 h, l;
    h.x = f2bf(v.x); h.y = f2bf(v.y); h.z = f2bf(v.z); h.w = f2bf(v.w);
    l.x = f2bf(v.x - bf2f(h.x)); l.y = f2bf(v.y - bf2f(h.y));
    l.z = f2bf(v.z - bf2f(h.z)); l.w = f2bf(v.w - bf2f(h.w));
    ((ushort4*)xh)[i] = h;
    ((ushort4*)xl4)[i] = l;
  }
}

// ---------------------------------------------------------------- weights -> K-major bf16 hi/lo
// whT/wlT[n*128 + k]; n<128 -> Wg col n, else Wa col n-128.
__global__ __launch_bounds__(128) void k_wprep(const float* __restrict__ Wg, const float* __restrict__ Wa,
                                               ushort_t* __restrict__ whT, ushort_t* __restrict__ wlT) {
  int n = blockIdx.x;      // 0..383
  int k = threadIdx.x;     // 0..127
  float v = (n < DOUT) ? Wg[(size_t)k * DOUT + n] : Wa[(size_t)k * TCOLS + (n - DOUT)];
  ushort_t h = f2bf(v);
  whT[(size_t)n * DIN + k] = h;
  wlT[(size_t)n * DIN + k] = f2bf(v - bf2f(h));
}

// ---------------------------------------------------------------- hierarchical scan, stage 1
__global__ __launch_bounds__(256) void k_scan1(const int* __restrict__ degc, int* __restrict__ offs,
                                               int* __restrict__ bsums, int N) {
  __shared__ int s[256];
  int tid = threadIdx.x;
  int base = blockIdx.x * 1024 + tid * 4;
  int c[4], e[4];
#pragma unroll
  for (int q = 0; q < 4; ++q) c[q] = (base + q < N) ? (degc[base + q] - 1) : 0;
  e[0] = 0; e[1] = c[0]; e[2] = e[1] + c[1]; e[3] = e[2] + c[2];
  int tsum = e[3] + c[3];
  s[tid] = tsum; __syncthreads();
  for (int off = 1; off < 256; off <<= 1) {
    int v = (tid >= off) ? s[tid - off] : 0;
    __syncthreads();
    s[tid] += v;
    __syncthreads();
  }
  int tb = s[tid] - tsum;
#pragma unroll
  for (int q = 0; q < 4; ++q) if (base + q < N) offs[base + q] = tb + e[q];
  if (tid == 255) bsums[blockIdx.x] = s[255];
}

// stage 2: exclusive scan of block sums (NBLK <= 128)
__global__ __launch_bounds__(128) void k_scan2(const int* __restrict__ bsums, int* __restrict__ boff,
                                               int* __restrict__ offs, int NBLK, int N) {
  __shared__ int s[128];
  int tid = threadIdx.x;
  int v = (tid < NBLK) ? bsums[tid] : 0;
  s[tid] = v; __syncthreads();
  for (int off = 1; off < 128; off <<= 1) {
    int u = (tid >= off) ? s[tid - off] : 0;
    __syncthreads();
    s[tid] += u;
    __syncthreads();
  }
  boff[tid] = s[tid] - v;
  if (tid == 127) offs[N] = s[127];   // total = E
}

// stage 3: add block offsets; dinv = rsqrt(deg); cursor = 0
__global__ __launch_bounds__(256) void k_scan3(int* __restrict__ offs, const int* __restrict__ boff,
                                               const int* __restrict__ degc, float* __restrict__ dinv,
                                               int* __restrict__ cursor, int N) {
  int i = blockIdx.x * 256 + threadIdx.x;
  if (i < N) {
    offs[i] += boff[i >> 10];
    dinv[i] = rsqrtf((float)degc[i]);
    cursor[i] = 0;
  }
}

// ---------------------------------------------------------------- CSR scatter: (src, norm) packed int2
__global__ __launch_bounds__(256) void k_scatter(const int* __restrict__ ei, const int* __restrict__ offs,
                                                 int* __restrict__ cursor, const float* __restrict__ dinv,
                                                 int2* __restrict__ csr, int E) {
  int e = blockIdx.x * 256 + threadIdx.x;
  if (e < E) {
    int s = ei[e];          // src
    int d = ei[E + e];      // dst
    int pos = atomicAdd(&cursor[d], 1);
    int2 q;
    q.x = s;
    q.y = __float_as_int(dinv[s] * dinv[d]);
    csr[offs[d] + pos] = q;
  }
}

// ---------------------------------------------------------------- fused GEMM via MFMA (split bf16, 3-pass):
// h = x@Wg (bf16 out); t = relu(x@Wa + ba) (bf16 out).
// Grid: (3 col-blocks of 128) x (row-blocks of 128). Block 256 thr = 4 waves (2x2 of 64x64).
__global__ __launch_bounds__(256) void k_gemm1_mfma(const ushort_t* __restrict__ xh,
                                                    const ushort_t* __restrict__ xl4,
                                                    const ushort_t* __restrict__ whT,
                                                    const ushort_t* __restrict__ wlT,
                                                    const float* __restrict__ ba,
                                                    ushort_t* __restrict__ hs, ushort_t* __restrict__ t,
                                                    int N) {
  int tid = threadIdx.x;
  int lane = tid & 63;
  int wave = tid >> 6;
  int wr = wave >> 1, wc = wave & 1;
  int colblk = blockIdx.x;                 // 0..2
  int rowbase = blockIdx.y * 128 + wr * 64;
  int gcb = colblk * 128 + wc * 64;        // global col base of this wave (0..383)
  int lr = lane & 15;
  int lk = (lane >> 4) * 8;

  int rows[4];
#pragma unroll
  for (int m = 0; m < 4; ++m) {
    int r = rowbase + m * 16 + lr;
    rows[m] = (r < N) ? r : (N - 1);
  }

  f32x4 acc[4][4] = {};

#pragma unroll
  for (int s = 0; s < 4; ++s) {
    int k0 = s * 32 + lk;
    bf16x8 ah[4], al[4], bh[4], bl[4];
#pragma unroll
    for (int m = 0; m < 4; ++m) {
      ah[m] = *(const bf16x8*)&xh[(size_t)rows[m] * DIN + k0];
      al[m] = *(const bf16x8*)&xl4[(size_t)rows[m] * DIN + k0];
    }
#pragma unroll
    for (int n = 0; n < 4; ++n) {
      int gc = gcb + n * 16 + lr;
      bh[n] = *(const bf16x8*)&whT[(size_t)gc * DIN + k0];
      bl[n] = *(const bf16x8*)&wlT[(size_t)gc * DIN + k0];
    }
#pragma unroll
    for (int m = 0; m < 4; ++m)
#pragma unroll
      for (int n = 0; n < 4; ++n) {
        acc[m][n] = __builtin_amdgcn_mfma_f32_16x16x32_bf16(ah[m], bl[n], acc[m][n], 0, 0, 0);
        acc[m][n] = __builtin_amdgcn_mfma_f32_16x16x32_bf16(al[m], bh[n], acc[m][n], 0, 0, 0);
        acc[m][n] = __builtin_amdgcn_mfma_f32_16x16x32_bf16(ah[m], bh[n], acc[m][n], 0, 0, 0);
      }
  }

  int rq = (lane >> 4) * 4;
  if (colblk == 0) {
    // cols 0..127 -> hs (no bias, no relu)
#pragma unroll
    for (int m = 0; m < 4; ++m)
#pragma unroll
      for (int i = 0; i < 4; ++i) {
        int row = rowbase + m * 16 + rq + i;
        if (row < N) {
#pragma unroll
          for (int n = 0; n < 4; ++n)
            hs[(size_t)row * DOUT + gcb + n * 16 + lr] = f2bf(acc[m][n][i]);
        }
      }
  } else {
    float bav[4];
#pragma unroll
    for (int n = 0; n < 4; ++n) bav[n] = ba[gcb - DOUT + n * 16 + lr];
#pragma unroll
    for (int m = 0; m < 4; ++m)
#pragma unroll
      for (int i = 0; i < 4; ++i) {
        int row = rowbase + m * 16 + rq + i;
        if (row < N) {
#pragma unroll
          for (int n = 0; n < 4; ++n)
            t[(size_t)row * TCOLS + gcb - DOUT + n * 16 + lr] =
                f2bf(fmaxf(acc[m][n][i] + bav[n], 0.f));
        }
      }
  }
}

// ---------------------------------------------------------------- VtZ (64x64) + colsum(U),colsum(V)
// R2: grid 1024 (4 blocks/CU); thread owns 4x4 outer-product patch (2 ds_read_b128/row).
__global__ __launch_bounds__(256) void k_red(const ushort_t* __restrict__ t, float* __restrict__ VtZ,
                                             float* __restrict__ colsum, int N) {
  __shared__ float uvz[16 * 192];   // cols 0..191 of t (U,V,Z)
  int tid = threadIdx.x;
  int RB = (N + gridDim.x - 1) / gridDim.x;
  int row0 = blockIdx.x * RB;
  int rowend = min(row0 + RB, N);
  int k0 = (tid >> 4) * 4;     // V-col base (0..60)
  int z0 = (tid & 15) * 4;     // Z-col base (0..60)
  float acc[4][4] = {};
  float cs = 0.f;
  for (int r0 = row0; r0 < rowend; r0 += 16) {
    for (int idx = tid; idx < 16 * 48; idx += 256) {
      int r = idx / 48, c4 = idx - r * 48;
      int row = r0 + r;
      float4 f;
      if (row < rowend) {
        ushort4 u = ((const ushort4*)&t[(size_t)row * TCOLS])[c4];
        f = make_float4(bf2f(u.x), bf2f(u.y), bf2f(u.z), bf2f(u.w));
      } else {
        f = make_float4(0.f, 0.f, 0.f, 0.f);
      }
      *(float4*)&uvz[r * 192 + c4 * 4] = f;
    }
    __syncthreads();
#pragma unroll
    for (int r = 0; r < 16; ++r) {
      float4 v = *(const float4*)&uvz[r * 192 + 64 + k0];
      float4 z = *(const float4*)&uvz[r * 192 + 128 + z0];
      acc[0][0] += v.x * z.x; acc[0][1] += v.x * z.y; acc[0][2] += v.x * z.z; acc[0][3] += v.x * z.w;
      acc[1][0] += v.y * z.x; acc[1][1] += v.y * z.y; acc[1][2] += v.y * z.z; acc[1][3] += v.y * z.w;
      acc[2][0] += v.z * z.x; acc[2][1] += v.z * z.y; acc[2][2] += v.z * z.z; acc[2][3] += v.z * z.w;
      acc[3][0] += v.w * z.x; acc[3][1] += v.w * z.y; acc[3][2] += v.w * z.z; acc[3][3] += v.w * z.w;
    }
    if (tid < 128) {
#pragma unroll
      for (int r = 0; r < 16; ++r) cs += uvz[r * 192 + tid];
    }
    __syncthreads();
  }
#pragma unroll
  for (int i = 0; i < 4; ++i)
#pragma unroll
    for (int j = 0; j < 4; ++j) atomicAdd(&VtZ[(k0 + i) * 64 + z0 + j], acc[i][j]);
  if (tid < 128) atomicAdd(&colsum[tid], cs);
}

// ---------------------------------------------------------------- D = N / dot(colsumU, colsumV)
__global__ __launch_bounds__(64) void k_d(const float* __restrict__ colsum, float* __restrict__ Dws, int N) {
  __shared__ float s[64];
  int k = threadIdx.x;
  s[k] = colsum[k] * colsum[64 + k];
  __syncthreads();
  for (int off = 32; off > 0; off >>= 1) {
    if (k < off) s[k] += s[k + off];
    __syncthreads();
  }
  if (k == 0) {
    float p = s[0];
    Dws[0] = (p != 0.f) ? ((float)N / p) : 0.f;
  }
}

// ---------------------------------------------------------------- Weff^T (K-major) build
__global__ __launch_bounds__(256) void k_prep(const float* __restrict__ VtZ,
                                              const float* __restrict__ Dws,
                                              const float* __restrict__ Wr,
                                              ushort_t* __restrict__ weffT) {
  int c = blockIdx.x;        // 0..127
  int k = threadIdx.x;       // 0..255
  float v;
  if (k < 128 || k >= 192) {
    v = Wr[(size_t)k * DOUT + c];
  } else {
    float Dv = Dws[0];
    int kk = k - 128;
    float acc = 0.f;
#pragma unroll 8
    for (int j = 0; j < 64; ++j)
      acc += VtZ[kk * 64 + j] * Wr[(size_t)(128 + j) * DOUT + c];
    v = acc * Dv;
  }
  weffT[(size_t)c * 256 + k] = f2bf(v);
}

// ---------------------------------------------------------------- out = [xl | U | T] @ Weff + br  (bf16 MFMA, fp32 out)
__global__ __launch_bounds__(256) void k_out_mfma(const ushort_t* __restrict__ xl,
                                                  const ushort_t* __restrict__ t,
                                                  const ushort_t* __restrict__ weffT,
                                                  const float* __restrict__ br,
                                                  float* __restrict__ out, int N) {
  int tid = threadIdx.x;
  int lane = tid & 63;
  int wave = tid >> 6;
  int wr = wave >> 1, wc = wave & 1;
  int rowbase = blockIdx.x * 128 + wr * 64;
  int cbase = wc * 64;
  int lr = lane & 15;
  int lk = (lane >> 4) * 8;

  int rows[4];
#pragma unroll
  for (int m = 0; m < 4; ++m) {
    int r = rowbase + m * 16 + lr;
    rows[m] = (r < N) ? r : (N - 1);
  }

  f32x4 acc[4][4] = {};

#pragma unroll
  for (int s = 0; s < 8; ++s) {
    int k0 = s * 32 + lk;
    bf16x8 a[4], b[4];
#pragma unroll
    for (int m = 0; m < 4; ++m) {
      const ushort_t* ap;
      if (s < 4)      ap = &xl[(size_t)rows[m] * DOUT + k0];
      else if (s < 6) ap = &t[(size_t)rows[m] * TCOLS + (k0 - 128)];
      else            ap = &t[(size_t)rows[m] * TCOLS + k0];
      a[m] = *(const bf16x8*)ap;
    }
#pragma unroll
    for (int n = 0; n < 4; ++n) {
      int c = cbase + n * 16 + lr;
      b[n] = *(const bf16x8*)&weffT[(size_t)c * 256 + k0];
    }
#pragma unroll
    for (int m = 0; m < 4; ++m)
#pragma unroll
      for (int n = 0; n < 4; ++n)
        acc[m][n] = __builtin_amdgcn_mfma_f32_16x16x32_bf16(a[m], b[n], acc[m][n], 0, 0, 0);
  }

  float brv[4];
#pragma unroll
  for (int n = 0; n < 4; ++n) brv[n] = br[cbase + n * 16 + lr];

  int rq = (lane >> 4) * 4;
#pragma unroll
  for (int m = 0; m < 4; ++m) {
#pragma unroll
    for (int i = 0; i < 4; ++i) {
      int row = rowbase + m * 16 + rq + i;
      if (row < N) {
#pragma unroll
        for (int n = 0; n < 4; ++n)
          out[(size_t)row * DOUT + cbase + n * 16 + lr] = acc[m][n][i] + brv[n];
      }
    }
  }
}

// ---------------------------------------------------------------- CSR gather-aggregate
__global__ __launch_bounds__(256) void k_aggn(const ushort_t* __restrict__ hs, const int2* __restrict__ csr,
                                              const int* __restrict__ offs, const float* __restrict__ dinv,
                                              const float* __restrict__ bg,
                                              ushort_t* __restrict__ xl, int N) {
  int node = blockIdx.x * 4 + (threadIdx.x >> 6);
  int lane = threadIdx.x & 63;
  if (node >= N) return;
  int c2 = 2 * lane;
  float dn = dinv[node];
  ushort2 u = *(const ushort2*)&hs[(size_t)node * DOUT + c2];
  float a0 = dn * dn * bf2f(u.x);
  float a1 = dn * dn * bf2f(u.y);
  int e = offs[node], e1 = offs[node + 1];
  for (; e + 4 <= e1; e += 4) {
    int2 q0 = csr[e], q1 = csr[e + 1], q2 = csr[e + 2], q3 = csr[e + 3];
    ushort2 r0 = *(const ushort2*)&hs[(size_t)q0.x * DOUT + c2];
    ushort2 r1 = *(const ushort2*)&hs[(size_t)q1.x * DOUT + c2];
    ushort2 r2 = *(const ushort2*)&hs[(size_t)q2.x * DOUT + c2];
    ushort2 r3 = *(const ushort2*)&hs[(size_t)q3.x * DOUT + c2];
    float n0 = __int_as_float(q0.y), n1 = __int_as_float(q1.y);
    float n2 = __int_as_float(q2.y), n3 = __int_as_float(q3.y);
    a0 += n0 * bf2f(r0.x) + n1 * bf2f(r1.x) + n2 * bf2f(r2.x) + n3 * bf2f(r3.x);
    a1 += n0 * bf2f(r0.y) + n1 * bf2f(r1.y) + n2 * bf2f(r2.y) + n3 * bf2f(r3.y);
  }
  for (; e < e1; ++e) {
    int2 q = csr[e];
    ushort2 r = *(const ushort2*)&hs[(size_t)q.x * DOUT + c2];
    float n0 = __int_as_float(q.y);
    a0 += n0 * bf2f(r.x);
    a1 += n0 * bf2f(r.y);
  }
  ushort2 o;
  o.x = f2bf(fmaxf(a0 + bg[c2], 0.f));
  o.y = f2bf(fmaxf(a1 + bg[c2 + 1], 0.f));
  *(ushort2*)&xl[(size_t)node * DOUT + c2] = o;
}

// ---------------------------------------------------------------- launch
extern "C" void kernel_launch(void* const* d_in, const int* in_sizes, int n_in,
                              void* d_out, int out_size, void* d_ws, size_t ws_size,
                              hipStream_t stream) {
  const float* x  = (const float*)d_in[0];
  const int* ei   = (const int*)d_in[1];
  const float* Wg = (const float*)d_in[2];
  const float* bg = (const float*)d_in[3];
  const float* Wa = (const float*)d_in[4];
  const float* ba = (const float*)d_in[5];
  const float* Wr = (const float*)d_in[6];
  const float* br = (const float*)d_in[7];
  float* out = (float*)d_out;     // fp32 output

  const int N = in_sizes[0] / DIN;
  const int E = in_sizes[1] / 2;

  char* p = (char*)d_ws;
  auto alloc = [&](size_t bytes) {
    char* r = p;
    p += (bytes + 255) & ~(size_t)255;
    return r;
  };
  float* Dws    = (float*)alloc(256);
  float* colsum = (float*)alloc(128 * 4);
  float* VtZ    = (float*)alloc(4096 * 4);
  int*   bsums  = (int*)alloc(1024);
  int*   boff   = (int*)alloc(1024);
  ushort_t* weffT = (ushort_t*)alloc(128 * 256 * 2);        // bf16 Weff^T (K-major)
  ushort_t* whT = (ushort_t*)alloc((size_t)WCOLS * DIN * 2);// bf16 [Wg|Wa]^T hi
  ushort_t* wlT = (ushort_t*)alloc((size_t)WCOLS * DIN * 2);// bf16 [Wg|Wa]^T lo
  int*   degc   = (int*)alloc((size_t)N * 4);
  float* dinv   = (float*)alloc((size_t)N * 4);
  int*   offs   = (int*)alloc((size_t)(N + 1) * 4);
  int*   cursor = (int*)alloc((size_t)N * 4);
  int2*  csr    = (int2*)alloc((size_t)E * 8);              // (src, norm) per edge
  ushort_t* xh  = (ushort_t*)alloc((size_t)N * DIN * 2);    // bf16 x hi
  ushort_t* xlo = (ushort_t*)alloc((size_t)N * DIN * 2);    // bf16 x lo
  ushort_t* hs  = (ushort_t*)alloc((size_t)N * DOUT * 2);   // bf16 x@Wg
  ushort_t* t   = (ushort_t*)alloc((size_t)N * TCOLS * 2);  // bf16 relu(x@Wa+ba)
  ushort_t* xl  = (ushort_t*)alloc((size_t)N * DOUT * 2);   // bf16 x_local
  (void)ws_size; (void)n_in; (void)out_size;

  const int GN = (N + 255) / 256;
  const int GE = (E + 255) / 256;
  const int NBLK = (N + 1023) / 1024;   // <= 128 for N <= 131072

  k_init<<<GN, 256, 0, stream>>>(degc, VtZ, colsum, N);
  k_deg<<<GE, 256, 0, stream>>>(ei, degc, E);
  k_split<<<2048, 256, 0, stream>>>(x, xh, xlo, N * DIN / 4);
  k_wprep<<<WCOLS, 128, 0, stream>>>(Wg, Wa, whT, wlT);
  k_scan1<<<NBLK, 256, 0, stream>>>(degc, offs, bsums, N);
  k_scan2<<<1, 128, 0, stream>>>(bsums, boff, offs, NBLK, N);
  k_scan3<<<GN, 256, 0, stream>>>(offs, boff, degc, dinv, cursor, N);
  k_scatter<<<GE, 256, 0, stream>>>(ei, offs, cursor, dinv, csr, E);
  k_gemm1_mfma<<<dim3(3, (N + 127) / 128), 256, 0, stream>>>(xh, xlo, whT, wlT, ba, hs, t, N);
  k_red<<<1024, 256, 0, stream>>>(t, VtZ, colsum, N);
  k_d<<<1, 64, 0, stream>>>(colsum, Dws, N);
  k_prep<<<128, 256, 0, stream>>>(VtZ, Dws, Wr, weffT);
  k_aggn<<<(N + 3) / 4, 256, 0, stream>>>(hs, csr, offs, dinv, bg, xl, N);
  k_out_mfma<<<(N + 127) / 128, 256, 0, stream>>>(xl, t, weffT, br, out, N);
}

// Round 3
// 517.495 us; speedup vs baseline: 1.6674x; 1.2051x over previous
//
#include <hip/hip_runtime.h>

// GCN + low-rank global attention (LRGA), N=100k, E=1.6M, D=128, K=64.
// R1: k_out -> bf16 MFMA with folded Weff.
// R2: k_gemm1 -> split-bf16 (hi/lo) MFMA 3-pass.
// R3: k_red -> atomic-free two-stage reduction; V^T@Z via MFMA with direct-from-global
//     fragments (was 4.2M contended f32 atomics = ~100us serialization).
#define DIN   128
#define DOUT  128
#define KR    64
#define TCOLS 256   // 4*K
#define WCOLS 384   // DOUT + TCOLS
#define P_RED 1024  // stage-1 partial blocks
#define PSTR  4224  // 4096 VtZ + 128 colsum

typedef unsigned short ushort_t;
typedef __attribute__((ext_vector_type(8))) short bf16x8;
typedef __attribute__((ext_vector_type(4))) float f32x4;

__device__ __forceinline__ float bf2f(unsigned short u) {
  return __uint_as_float(((unsigned int)u) << 16);
}
__device__ __forceinline__ unsigned short f2bf(float f) {
  unsigned int b = __float_as_uint(f);
  b = b + 0x7FFFu + ((b >> 16) & 1u);
  return (unsigned short)(b >> 16);
}

// ---------------------------------------------------------------- init
__global__ __launch_bounds__(256) void k_init(int* __restrict__ degc, float* __restrict__ VtZ,
                                              float* __restrict__ colsum, int N) {
  int i = blockIdx.x * 256 + threadIdx.x;
  if (i < N) degc[i] = 1;            // self-loop gives deg >= 1
  if (i < 4096) VtZ[i] = 0.f;
  if (i < 128) colsum[i] = 0.f;
}

// ---------------------------------------------------------------- degree (in-degree via dst row)
__global__ __launch_bounds__(256) void k_deg(const int* __restrict__ ei, int* __restrict__ degc, int E) {
  int e = blockIdx.x * 256 + threadIdx.x;
  if (e < E) atomicAdd(&degc[ei[E + e]], 1);
}

// ---------------------------------------------------------------- x -> bf16 hi/lo split (for MFMA)
__global__ __launch_bounds__(256) void k_split(const float* __restrict__ x,
                                               ushort_t* __restrict__ xh, ushort_t* __restrict__ xl4,
                                               int total4) {
  int i = blockIdx.x * 256 + threadIdx.x;
  int stride = gridDim.x * 256;
  for (; i < total4; i += stride) {
    float4 v = ((const float4*)x)[i];
    ushort4 h, l;
    h.x = f2bf(v.x); h.y = f2bf(v.y); h.z = f2bf(v.z); h.w = f2bf(v.w);
    l.x = f2bf(v.x - bf2f(h.x)); l.y = f2bf(v.y - bf2f(h.y));
    l.z = f2bf(v.z - bf2f(h.z)); l.w = f2bf(v.w - bf2f(h.w));
    ((ushort4*)xh)[i] = h;
    ((ushort4*)xl4)[i] = l;
  }
}

// ---------------------------------------------------------------- weights -> K-major bf16 hi/lo
__global__ __launch_bounds__(128) void k_wprep(const float* __restrict__ Wg, const float* __restrict__ Wa,
                                               ushort_t* __restrict__ whT, ushort_t* __restrict__ wlT) {
  int n = blockIdx.x;      // 0..383
  int k = threadIdx.x;     // 0..127
  float v = (n < DOUT) ? Wg[(size_t)k * DOUT + n] : Wa[(size_t)k * TCOLS + (n - DOUT)];
  ushort_t h = f2bf(v);
  whT[(size_t)n * DIN + k] = h;
  wlT[(size_t)n * DIN + k] = f2bf(v - bf2f(h));
}

// ---------------------------------------------------------------- hierarchical scan, stage 1
__global__ __launch_bounds__(256) void k_scan1(const int* __restrict__ degc, int* __restrict__ offs,
                                               int* __restrict__ bsums, int N) {
  __shared__ int s[256];
  int tid = threadIdx.x;
  int base = blockIdx.x * 1024 + tid * 4;
  int c[4], e[4];
#pragma unroll
  for (int q = 0; q < 4; ++q) c[q] = (base + q < N) ? (degc[base + q] - 1) : 0;
  e[0] = 0; e[1] = c[0]; e[2] = e[1] + c[1]; e[3] = e[2] + c[2];
  int tsum = e[3] + c[3];
  s[tid] = tsum; __syncthreads();
  for (int off = 1; off < 256; off <<= 1) {
    int v = (tid >= off) ? s[tid - off] : 0;
    __syncthreads();
    s[tid] += v;
    __syncthreads();
  }
  int tb = s[tid] - tsum;
#pragma unroll
  for (int q = 0; q < 4; ++q) if (base + q < N) offs[base + q] = tb + e[q];
  if (tid == 255) bsums[blockIdx.x] = s[255];
}

// stage 2: exclusive scan of block sums (NBLK <= 128)
__global__ __launch_bounds__(128) void k_scan2(const int* __restrict__ bsums, int* __restrict__ boff,
                                               int* __restrict__ offs, int NBLK, int N) {
  __shared__ int s[128];
  int tid = threadIdx.x;
  int v = (tid < NBLK) ? bsums[tid] : 0;
  s[tid] = v; __syncthreads();
  for (int off = 1; off < 128; off <<= 1) {
    int u = (tid >= off) ? s[tid - off] : 0;
    __syncthreads();
    s[tid] += u;
    __syncthreads();
  }
  boff[tid] = s[tid] - v;
  if (tid == 127) offs[N] = s[127];   // total = E
}

// stage 3: add block offsets; dinv = rsqrt(deg); cursor = 0
__global__ __launch_bounds__(256) void k_scan3(int* __restrict__ offs, const int* __restrict__ boff,
                                               const int* __restrict__ degc, float* __restrict__ dinv,
                                               int* __restrict__ cursor, int N) {
  int i = blockIdx.x * 256 + threadIdx.x;
  if (i < N) {
    offs[i] += boff[i >> 10];
    dinv[i] = rsqrtf((float)degc[i]);
    cursor[i] = 0;
  }
}

// ---------------------------------------------------------------- CSR scatter: (src, norm) packed int2
__global__ __launch_bounds__(256) void k_scatter(const int* __restrict__ ei, const int* __restrict__ offs,
                                                 int* __restrict__ cursor, const float* __restrict__ dinv,
                                                 int2* __restrict__ csr, int E) {
  int e = blockIdx.x * 256 + threadIdx.x;
  if (e < E) {
    int s = ei[e];          // src
    int d = ei[E + e];      // dst
    int pos = atomicAdd(&cursor[d], 1);
    int2 q;
    q.x = s;
    q.y = __float_as_int(dinv[s] * dinv[d]);
    csr[offs[d] + pos] = q;
  }
}

// ---------------------------------------------------------------- fused GEMM via MFMA (split bf16, 3-pass)
__global__ __launch_bounds__(256) void k_gemm1_mfma(const ushort_t* __restrict__ xh,
                                                    const ushort_t* __restrict__ xl4,
                                                    const ushort_t* __restrict__ whT,
                                                    const ushort_t* __restrict__ wlT,
                                                    const float* __restrict__ ba,
                                                    ushort_t* __restrict__ hs, ushort_t* __restrict__ t,
                                                    int N) {
  int tid = threadIdx.x;
  int lane = tid & 63;
  int wave = tid >> 6;
  int wr = wave >> 1, wc = wave & 1;
  int colblk = blockIdx.x;                 // 0..2
  int rowbase = blockIdx.y * 128 + wr * 64;
  int gcb = colblk * 128 + wc * 64;        // global col base of this wave (0..383)
  int lr = lane & 15;
  int lk = (lane >> 4) * 8;

  int rows[4];
#pragma unroll
  for (int m = 0; m < 4; ++m) {
    int r = rowbase + m * 16 + lr;
    rows[m] = (r < N) ? r : (N - 1);
  }

  f32x4 acc[4][4] = {};

#pragma unroll
  for (int s = 0; s < 4; ++s) {
    int k0 = s * 32 + lk;
    bf16x8 ah[4], al[4], bh[4], bl[4];
#pragma unroll
    for (int m = 0; m < 4; ++m) {
      ah[m] = *(const bf16x8*)&xh[(size_t)rows[m] * DIN + k0];
      al[m] = *(const bf16x8*)&xl4[(size_t)rows[m] * DIN + k0];
    }
#pragma unroll
    for (int n = 0; n < 4; ++n) {
      int gc = gcb + n * 16 + lr;
      bh[n] = *(const bf16x8*)&whT[(size_t)gc * DIN + k0];
      bl[n] = *(const bf16x8*)&wlT[(size_t)gc * DIN + k0];
    }
#pragma unroll
    for (int m = 0; m < 4; ++m)
#pragma unroll
      for (int n = 0; n < 4; ++n) {
        acc[m][n] = __builtin_amdgcn_mfma_f32_16x16x32_bf16(ah[m], bl[n], acc[m][n], 0, 0, 0);
        acc[m][n] = __builtin_amdgcn_mfma_f32_16x16x32_bf16(al[m], bh[n], acc[m][n], 0, 0, 0);
        acc[m][n] = __builtin_amdgcn_mfma_f32_16x16x32_bf16(ah[m], bh[n], acc[m][n], 0, 0, 0);
      }
  }

  int rq = (lane >> 4) * 4;
  if (colblk == 0) {
#pragma unroll
    for (int m = 0; m < 4; ++m)
#pragma unroll
      for (int i = 0; i < 4; ++i) {
        int row = rowbase + m * 16 + rq + i;
        if (row < N) {
#pragma unroll
          for (int n = 0; n < 4; ++n)
            hs[(size_t)row * DOUT + gcb + n * 16 + lr] = f2bf(acc[m][n][i]);
        }
      }
  } else {
    float bav[4];
#pragma unroll
    for (int n = 0; n < 4; ++n) bav[n] = ba[gcb - DOUT + n * 16 + lr];
#pragma unroll
    for (int m = 0; m < 4; ++m)
#pragma unroll
      for (int i = 0; i < 4; ++i) {
        int row = rowbase + m * 16 + rq + i;
        if (row < N) {
#pragma unroll
          for (int n = 0; n < 4; ++n)
            t[(size_t)row * TCOLS + gcb - DOUT + n * 16 + lr] =
                f2bf(fmaxf(acc[m][n][i] + bav[n], 0.f));
        }
      }
  }
}

// ---------------------------------------------------------------- VtZ + colsum, stage 1 (atomic-free)
// Per block: partial VtZ[64][64] via MFMA (A = V^T frag, B = Z frag, direct global reads)
// + partial colsum[128] in registers. Writes part[blk][4224]. No LDS staging, no per-tile barriers.
__global__ __launch_bounds__(256) void k_red(const ushort_t* __restrict__ t, float* __restrict__ part,
                                             int N) {
  __shared__ float csh[512];
  int tid = threadIdx.x;
  int lane = tid & 63;
  int w = tid >> 6;            // wave 0..3 -> V-col strip w*16
  int lr = lane & 15;
  int lk = (lane >> 4) * 8;
  int vcol = 64 + w * 16 + lr; // t-col of A-operand (V region)
  int col2 = lane * 2;         // colsum col pair (0..127)

  f32x4 acc[4] = {};
  float cs0 = 0.f, cs1 = 0.f;
  int ntiles = (N + 31) >> 5;

  for (int tile = blockIdx.x; tile < ntiles; tile += gridDim.x) {
    int r0 = tile * 32;
    const ushort_t* base = &t[(size_t)r0 * TCOLS];
    bf16x8 a, b[4];
    if (r0 + 32 <= N) {
#pragma unroll
      for (int j = 0; j < 8; ++j)
        ((short*)&a)[j] = (short)base[(size_t)(lk + j) * TCOLS + vcol];
#pragma unroll
      for (int n = 0; n < 4; ++n)
#pragma unroll
        for (int j = 0; j < 8; ++j)
          ((short*)&b[n])[j] = (short)base[(size_t)(lk + j) * TCOLS + 128 + n * 16 + lr];
#pragma unroll
      for (int j = 0; j < 8; ++j) {
        ushort2 u = *(const ushort2*)&base[(size_t)(w * 8 + j) * TCOLS + col2];
        cs0 += bf2f(u.x); cs1 += bf2f(u.y);
      }
    } else {
      // tail tile: zero-fill rows >= N
#pragma unroll
      for (int j = 0; j < 8; ++j) {
        int r = r0 + lk + j;
        ((short*)&a)[j] = (r < N) ? (short)t[(size_t)r * TCOLS + vcol] : (short)0;
      }
#pragma unroll
      for (int n = 0; n < 4; ++n)
#pragma unroll
        for (int j = 0; j < 8; ++j) {
          int r = r0 + lk + j;
          ((short*)&b[n])[j] = (r < N) ? (short)t[(size_t)r * TCOLS + 128 + n * 16 + lr] : (short)0;
        }
#pragma unroll
      for (int j = 0; j < 8; ++j) {
        int r = r0 + w * 8 + j;
        if (r < N) {
          ushort2 u = *(const ushort2*)&t[(size_t)r * TCOLS + col2];
          cs0 += bf2f(u.x); cs1 += bf2f(u.y);
        }
      }
    }
#pragma unroll
    for (int n = 0; n < 4; ++n)
      acc[n] = __builtin_amdgcn_mfma_f32_16x16x32_bf16(a, b[n], acc[n], 0, 0, 0);
  }

  float* pb = &part[(size_t)blockIdx.x * PSTR];
  int rq = (lane >> 4) * 4;
#pragma unroll
  for (int n = 0; n < 4; ++n)
#pragma unroll
    for (int i = 0; i < 4; ++i)
      pb[(w * 16 + rq + i) * 64 + n * 16 + lr] = acc[n][i];

  // colsum: reduce 4 wave-partials per column pair via LDS
  csh[tid] = cs0;
  csh[256 + tid] = cs1;
  __syncthreads();
  if (w == 0) {
    float t0 = csh[lane] + csh[64 + lane] + csh[128 + lane] + csh[192 + lane];
    float t1 = csh[256 + lane] + csh[320 + lane] + csh[384 + lane] + csh[448 + lane];
    pb[4096 + col2] = t0;
    pb[4096 + col2 + 1] = t1;
  }
}

// ---------------------------------------------------------------- stage 2: sum P_RED partials
__global__ __launch_bounds__(256) void k_redsum(const float* __restrict__ part,
                                                float* __restrict__ VtZ, float* __restrict__ colsum) {
  __shared__ float s[256];
  int tid = threadIdx.x;
  int j = blockIdx.x * 64 + (tid & 63);
  int bc = tid >> 6;           // 0..3
  float a = 0.f;
#pragma unroll 4
  for (int b = bc; b < P_RED; b += 4) a += part[(size_t)b * PSTR + j];
  s[tid] = a;
  __syncthreads();
  if (bc == 0) {
    float v = s[tid] + s[tid + 64] + s[tid + 128] + s[tid + 192];
    if (j < 4096) VtZ[j] = v;
    else colsum[j - 4096] = v;
  }
}

// ---------------------------------------------------------------- D = N / dot(colsumU, colsumV)
__global__ __launch_bounds__(64) void k_d(const float* __restrict__ colsum, float* __restrict__ Dws, int N) {
  __shared__ float s[64];
  int k = threadIdx.x;
  s[k] = colsum[k] * colsum[64 + k];
  __syncthreads();
  for (int off = 32; off > 0; off >>= 1) {
    if (k < off) s[k] += s[k + off];
    __syncthreads();
  }
  if (k == 0) {
    float p = s[0];
    Dws[0] = (p != 0.f) ? ((float)N / p) : 0.f;
  }
}

// ---------------------------------------------------------------- Weff^T (K-major) build
__global__ __launch_bounds__(256) void k_prep(const float* __restrict__ VtZ,
                                              const float* __restrict__ Dws,
                                              const float* __restrict__ Wr,
                                              ushort_t* __restrict__ weffT) {
  int c = blockIdx.x;        // 0..127
  int k = threadIdx.x;       // 0..255
  float v;
  if (k < 128 || k >= 192) {
    v = Wr[(size_t)k * DOUT + c];
  } else {
    float Dv = Dws[0];
    int kk = k - 128;
    float acc = 0.f;
#pragma unroll 8
    for (int j = 0; j < 64; ++j)
      acc += VtZ[kk * 64 + j] * Wr[(size_t)(128 + j) * DOUT + c];
    v = acc * Dv;
  }
  weffT[(size_t)c * 256 + k] = f2bf(v);
}

// ---------------------------------------------------------------- out = [xl | U | T] @ Weff + br  (bf16 MFMA, fp32 out)
__global__ __launch_bounds__(256) void k_out_mfma(const ushort_t* __restrict__ xl,
                                                  const ushort_t* __restrict__ t,
                                                  const ushort_t* __restrict__ weffT,
                                                  const float* __restrict__ br,
                                                  float* __restrict__ out, int N) {
  int tid = threadIdx.x;
  int lane = tid & 63;
  int wave = tid >> 6;
  int wr = wave >> 1, wc = wave & 1;
  int rowbase = blockIdx.x * 128 + wr * 64;
  int cbase = wc * 64;
  int lr = lane & 15;
  int lk = (lane >> 4) * 8;

  int rows[4];
#pragma unroll
  for (int m = 0; m < 4; ++m) {
    int r = rowbase + m * 16 + lr;
    rows[m] = (r < N) ? r : (N - 1);
  }

  f32x4 acc[4][4] = {};

#pragma unroll
  for (int s = 0; s < 8; ++s) {
    int k0 = s * 32 + lk;
    bf16x8 a[4], b[4];
#pragma unroll
    for (int m = 0; m < 4; ++m) {
      const ushort_t* ap;
      if (s < 4)      ap = &xl[(size_t)rows[m] * DOUT + k0];
      else if (s < 6) ap = &t[(size_t)rows[m] * TCOLS + (k0 - 128)];
      else            ap = &t[(size_t)rows[m] * TCOLS + k0];
      a[m] = *(const bf16x8*)ap;
    }
#pragma unroll
    for (int n = 0; n < 4; ++n) {
      int c = cbase + n * 16 + lr;
      b[n] = *(const bf16x8*)&weffT[(size_t)c * 256 + k0];
    }
#pragma unroll
    for (int m = 0; m < 4; ++m)
#pragma unroll
      for (int n = 0; n < 4; ++n)
        acc[m][n] = __builtin_amdgcn_mfma_f32_16x16x32_bf16(a[m], b[n], acc[m][n], 0, 0, 0);
  }

  float brv[4];
#pragma unroll
  for (int n = 0; n < 4; ++n) brv[n] = br[cbase + n * 16 + lr];

  int rq = (lane >> 4) * 4;
#pragma unroll
  for (int m = 0; m < 4; ++m) {
#pragma unroll
    for (int i = 0; i < 4; ++i) {
      int row = rowbase + m * 16 + rq + i;
      if (row < N) {
#pragma unroll
        for (int n = 0; n < 4; ++n)
          out[(size_t)row * DOUT + cbase + n * 16 + lr] = acc[m][n][i] + brv[n];
      }
    }
  }
}

// ---------------------------------------------------------------- CSR gather-aggregate
__global__ __launch_bounds__(256) void k_aggn(const ushort_t* __restrict__ hs, const int2* __restrict__ csr,
                                              const int* __restrict__ offs, const float* __restrict__ dinv,
                                              const float* __restrict__ bg,
                                              ushort_t* __restrict__ xl, int N) {
  int node = blockIdx.x * 4 + (threadIdx.x >> 6);
  int lane = threadIdx.x & 63;
  if (node >= N) return;
  int c2 = 2 * lane;
  float dn = dinv[node];
  ushort2 u = *(const ushort2*)&hs[(size_t)node * DOUT + c2];
  float a0 = dn * dn * bf2f(u.x);
  float a1 = dn * dn * bf2f(u.y);
  int e = offs[node], e1 = offs[node + 1];
  for (; e + 4 <= e1; e += 4) {
    int2 q0 = csr[e], q1 = csr[e + 1], q2 = csr[e + 2], q3 = csr[e + 3];
    ushort2 r0 = *(const ushort2*)&hs[(size_t)q0.x * DOUT + c2];
    ushort2 r1 = *(const ushort2*)&hs[(size_t)q1.x * DOUT + c2];
    ushort2 r2 = *(const ushort2*)&hs[(size_t)q2.x * DOUT + c2];
    ushort2 r3 = *(const ushort2*)&hs[(size_t)q3.x * DOUT + c2];
    float n0 = __int_as_float(q0.y), n1 = __int_as_float(q1.y);
    float n2 = __int_as_float(q2.y), n3 = __int_as_float(q3.y);
    a0 += n0 * bf2f(r0.x) + n1 * bf2f(r1.x) + n2 * bf2f(r2.x) + n3 * bf2f(r3.x);
    a1 += n0 * bf2f(r0.y) + n1 * bf2f(r1.y) + n2 * bf2f(r2.y) + n3 * bf2f(r3.y);
  }
  for (; e < e1; ++e) {
    int2 q = csr[e];
    ushort2 r = *(const ushort2*)&hs[(size_t)q.x * DOUT + c2];
    float n0 = __int_as_float(q.y);
    a0 += n0 * bf2f(r.x);
    a1 += n0 * bf2f(r.y);
  }
  ushort2 o;
  o.x = f2bf(fmaxf(a0 + bg[c2], 0.f));
  o.y = f2bf(fmaxf(a1 + bg[c2 + 1], 0.f));
  *(ushort2*)&xl[(size_t)node * DOUT + c2] = o;
}

// ---------------------------------------------------------------- launch
extern "C" void kernel_launch(void* const* d_in, const int* in_sizes, int n_in,
                              void* d_out, int out_size, void* d_ws, size_t ws_size,
                              hipStream_t stream) {
  const float* x  = (const float*)d_in[0];
  const int* ei   = (const int*)d_in[1];
  const float* Wg = (const float*)d_in[2];
  const float* bg = (const float*)d_in[3];
  const float* Wa = (const float*)d_in[4];
  const float* ba = (const float*)d_in[5];
  const float* Wr = (const float*)d_in[6];
  const float* br = (const float*)d_in[7];
  float* out = (float*)d_out;     // fp32 output

  const int N = in_sizes[0] / DIN;
  const int E = in_sizes[1] / 2;

  char* p = (char*)d_ws;
  auto alloc = [&](size_t bytes) {
    char* r = p;
    p += (bytes + 255) & ~(size_t)255;
    return r;
  };
  float* Dws    = (float*)alloc(256);
  float* colsum = (float*)alloc(128 * 4);
  float* VtZ    = (float*)alloc(4096 * 4);
  int*   bsums  = (int*)alloc(1024);
  int*   boff   = (int*)alloc(1024);
  ushort_t* weffT = (ushort_t*)alloc(128 * 256 * 2);        // bf16 Weff^T (K-major)
  ushort_t* whT = (ushort_t*)alloc((size_t)WCOLS * DIN * 2);// bf16 [Wg|Wa]^T hi
  ushort_t* wlT = (ushort_t*)alloc((size_t)WCOLS * DIN * 2);// bf16 [Wg|Wa]^T lo
  float* part   = (float*)alloc((size_t)P_RED * PSTR * 4);  // stage-1 partials (16.5 MB)
  int*   degc   = (int*)alloc((size_t)N * 4);
  float* dinv   = (float*)alloc((size_t)N * 4);
  int*   offs   = (int*)alloc((size_t)(N + 1) * 4);
  int*   cursor = (int*)alloc((size_t)N * 4);
  int2*  csr    = (int2*)alloc((size_t)E * 8);              // (src, norm) per edge
  ushort_t* xh  = (ushort_t*)alloc((size_t)N * DIN * 2);    // bf16 x hi
  ushort_t* xlo = (ushort_t*)alloc((size_t)N * DIN * 2);    // bf16 x lo
  ushort_t* hs  = (ushort_t*)alloc((size_t)N * DOUT * 2);   // bf16 x@Wg
  ushort_t* t   = (ushort_t*)alloc((size_t)N * TCOLS * 2);  // bf16 relu(x@Wa+ba)
  ushort_t* xl  = (ushort_t*)alloc((size_t)N * DOUT * 2);   // bf16 x_local
  (void)ws_size; (void)n_in; (void)out_size;

  const int GN = (N + 255) / 256;
  const int GE = (E + 255) / 256;
  const int NBLK = (N + 1023) / 1024;   // <= 128 for N <= 131072

  k_init<<<GN, 256, 0, stream>>>(degc, VtZ, colsum, N);
  k_deg<<<GE, 256, 0, stream>>>(ei, degc, E);
  k_split<<<2048, 256, 0, stream>>>(x, xh, xlo, N * DIN / 4);
  k_wprep<<<WCOLS, 128, 0, stream>>>(Wg, Wa, whT, wlT);
  k_scan1<<<NBLK, 256, 0, stream>>>(degc, offs, bsums, N);
  k_scan2<<<1, 128, 0, stream>>>(bsums, boff, offs, NBLK, N);
  k_scan3<<<GN, 256, 0, stream>>>(offs, boff, degc, dinv, cursor, N);
  k_scatter<<<GE, 256, 0, stream>>>(ei, offs, cursor, dinv, csr, E);
  k_gemm1_mfma<<<dim3(3, (N + 127) / 128), 256, 0, stream>>>(xh, xlo, whT, wlT, ba, hs, t, N);
  k_red<<<P_RED, 256, 0, stream>>>(t, part, N);
  k_redsum<<<PSTR / 64, 256, 0, stream>>>(part, VtZ, colsum);
  k_d<<<1, 64, 0, stream>>>(colsum, Dws, N);
  k_prep<<<128, 256, 0, stream>>>(VtZ, Dws, Wr, weffT);
  k_aggn<<<(N + 3) / 4, 256, 0, stream>>>(hs, csr, offs, dinv, bg, xl, N);
  k_out_mfma<<<(N + 127) / 128, 256, 0, stream>>>(xl, t, weffT, br, out, N);
}